// Round 14
// baseline (418.791 us; speedup 1.0000x reference)
//
#include <hip/hip_runtime.h>

#define NA    50000
#define NFEAT 512
#define HID   512
#define NC    128
#define AH    64
#define NE    800000
#define NHOP  4
#define NBUCK 196      // ceil(NA/256) buckets of 256 rows
#define CAPB  5120     // per-bucket capacity (mean 4082 -> 16 sigma headroom)

typedef __bf16 bf16x8 __attribute__((ext_vector_type(8)));
typedef float  f32x4  __attribute__((ext_vector_type(4)));

__device__ __forceinline__ unsigned short f2bf(float f){
  union { float f; unsigned u; } a; a.f = f;
  return (unsigned short)((a.u + 0x7fffu + ((a.u >> 16) & 1u)) >> 16);  // RNE
}
__device__ __forceinline__ float bf2f(unsigned short h){
  union { unsigned u; float f; } a; a.u = ((unsigned)h) << 16;
  return a.f;
}
__device__ __forceinline__ float uasf(unsigned u){
  union { unsigned u; float f; } a; a.u = u;
  return a.f;
}
__device__ __forceinline__ float tanh_fast(float x){
  x = fminf(15.f, fmaxf(-15.f, x));
  float e = __expf(2.f * x);
  return (e - 1.f) / (e + 1.f);
}

__device__ __forceinline__ void g2l16(const void* g, void* l){
  __builtin_amdgcn_global_load_lds(
      (const __attribute__((address_space(1))) void*)g,
      (__attribute__((address_space(3))) void*)l, 16, 0, 0);
}

// ---------------- merged weight prep + fill-zero (one launch) ----------------
// W2cT [256][512]: rows 0-127 = W2^T; rows 128-255 = (W2@Wg)^T  [zg = z@Wg = H@(W2@Wg)+b2@Wg]
// b2c  [256]:      0-127 = b2;  128-255 = b2@Wg
__global__ void prep_kernel(const float* __restrict__ W1, const float* __restrict__ W2,
                            const float* __restrict__ Wg, const float* __restrict__ Wa,
                            const float* __restrict__ b2,
                            unsigned short* __restrict__ W1T, unsigned short* __restrict__ W2cT,
                            unsigned short* __restrict__ WaT, float* __restrict__ b2c,
                            int* __restrict__ fill){
  const int b = blockIdx.x, tid = threadIdx.x;
  if (b < 1024){
    int i = b * 256 + tid;                       // 262144: W1T [512][512] = W1^T
    int n = i >> 9, k = i & 511;
    W1T[i] = f2bf(W1[(size_t)k * HID + n]);
  } else if (b < 1280){
    int i = (b - 1024) * 256 + tid;              // 65536: W2cT rows 0-127 = W2^T
    int n = i >> 9, k = i & 511;
    W2cT[i] = f2bf(W2[(size_t)k * NC + n]);
  } else if (b < 1536){
    int i = (b - 1280) * 256 + tid;              // 65536: W2cT rows 128-255 = (W2@Wg)^T
    int n = i >> 9, k = i & 511;
    float s = 0.f;
    for (int j = 0; j < 128; j++)
      s += W2[(size_t)k * NC + j] * Wg[(size_t)j * NC + n];
    W2cT[65536 + i] = f2bf(s);
  } else if (b < 1600){
    int i = (b - 1536) * 256 + tid;              // 16384: WaT packed [Wa_top|Wa_bot]
    int n = i >> 7, k = i & 127;
    float v = (n < 64) ? Wa[(size_t)k * AH + n] : Wa[(size_t)(128 + k) * AH + (n - 64)];
    WaT[i] = f2bf(v);
  } else if (b == 1600){
    if (tid < 128) b2c[tid] = b2[tid];
    else {
      int n = tid - 128;
      float s = 0.f;
      for (int j = 0; j < 128; j++) s += b2[j] * Wg[(size_t)j * NC + n];
      b2c[128 + n] = s;
    }
  } else {
    int i = (b - 1601) * 256 + tid;              // zero fill[784]
    if (i < NHOP * NBUCK) fill[i] = 0;
  }
}

// ---------------- wide MFMA GEMM: 128x256 tile, acc[4][8] ----------------
// OP=0: H = relu(x_f32 @ W1)          A=f32 (reg-staged cvt), N=512, 2 col-blocks,
//        XCD-affine (both col-blocks of a row on one XCD -> x row-tile 1x HBM).
// OP=1: [z|zg] = H @ [W2|W2@Wg] + b2c  A=bf16 via g2l16, N=256, 1 col-block.
// Per K-step/wave: 32 MFMA vs 6 staging issues (2x density of the 128x128 tile).
template<int OP>
__global__ __launch_bounds__(256) void gemm_wide(
    const void* __restrict__ Avoid, const unsigned short* __restrict__ BT,
    unsigned short* __restrict__ C0, unsigned short* __restrict__ C1,
    const float* __restrict__ bias)
{
  int row0, col0;
  if (OP == 0){
    const int xcd = blockIdx.x & 7, slot = blockIdx.x >> 3;
    const int r = xcd * 49 + (slot >> 1);
    if (r >= 391) return;
    row0 = r * 128; col0 = (slot & 1) * 256;
  } else {
    row0 = blockIdx.x * 128; col0 = 0;
  }
  const int K = 512;
  const float*          A32 = (const float*)Avoid;
  const unsigned short* A16 = (const unsigned short*)Avoid;
  __shared__ unsigned short As[128 * 32];
  __shared__ unsigned short Bs[256 * 32];
  const int tid = threadIdx.x;
  const int wave = tid >> 6, lane = tid & 63;
  const int wr = (wave >> 1) * 64, wcb = (wave & 1) * 128;
  f32x4 acc[4][8];
  #pragma unroll
  for (int m = 0; m < 4; m++)
    #pragma unroll
    for (int n = 0; n < 8; n++) acc[m][n] = (f32x4){0.f, 0.f, 0.f, 0.f};
  const int lrow = lane >> 2, lk = (lane & 3) * 8;

  for (int k0 = 0; k0 < K; k0 += 32){
    __syncthreads();
    #pragma unroll
    for (int j = 0; j < 2; j++){                 // A: 128 rows, 2 iters/wave
      const int rb = (wave * 2 + j) * 16;
      const int ra = rb + lrow;
      int gr = row0 + ra; gr = gr < NA ? gr : NA - 1;
      if (OP == 0){
        const float* src = A32 + (size_t)gr * K + k0 + lk;
        float4 f0 = *reinterpret_cast<const float4*>(src);
        float4 f1 = *reinterpret_cast<const float4*>(src + 4);
        bf16x8 a;
        a[0] = (__bf16)f0.x; a[1] = (__bf16)f0.y; a[2] = (__bf16)f0.z; a[3] = (__bf16)f0.w;
        a[4] = (__bf16)f1.x; a[5] = (__bf16)f1.y; a[6] = (__bf16)f1.z; a[7] = (__bf16)f1.w;
        *reinterpret_cast<bf16x8*>(&As[ra * 32 + lk]) = a;    // addr = lane*16: linear
      } else {
        g2l16(A16 + (size_t)gr * K + k0 + lk, As + rb * 32);
      }
    }
    #pragma unroll
    for (int j = 0; j < 4; j++){                 // B: 256 rows, 4 iters/wave
      const int rb = (wave * 4 + j) * 16;
      const int gc = col0 + rb + lrow;           // OP0 < 512, OP1 < 256
      g2l16(BT + (size_t)gc * K + k0 + lk, Bs + rb * 32);
    }
    __syncthreads();
    bf16x8 af[4], bfr[8];
    #pragma unroll
    for (int m = 0; m < 4; m++)
      af[m] = *reinterpret_cast<const bf16x8*>(&As[(wr + m * 16 + (lane & 15)) * 32 + (lane >> 4) * 8]);
    #pragma unroll
    for (int n = 0; n < 8; n++)
      bfr[n] = *reinterpret_cast<const bf16x8*>(&Bs[(wcb + n * 16 + (lane & 15)) * 32 + (lane >> 4) * 8]);
    #pragma unroll
    for (int m = 0; m < 4; m++)
      #pragma unroll
      for (int n = 0; n < 8; n++)
        acc[m][n] = __builtin_amdgcn_mfma_f32_16x16x32_bf16(af[m], bfr[n], acc[m][n], 0, 0, 0);
  }

  const int rbase = row0 + wr + (lane >> 4) * 4;
  const int cbase = wcb + (lane & 15);           // local col within 256-tile
  #pragma unroll
  for (int m = 0; m < 4; m++){
    #pragma unroll
    for (int n = 0; n < 8; n++){
      const int cl = cbase + n * 16;
      #pragma unroll
      for (int i = 0; i < 4; i++){
        const int row = rbase + m * 16 + i;
        if (row < NA){
          float v = acc[m][n][i];
          if (OP == 0){
            v = v > 0.f ? v : 0.f;
            C0[(size_t)row * HID + col0 + cl] = f2bf(v);
          } else {
            v += bias[cl];
            unsigned short o = f2bf(v);
            if (cl < 128) C0[(size_t)row * NC + cl] = o;
            else          C1[(size_t)row * NC + (cl - 128)] = o;
          }
        }
      }
    }
  }
}

// ---------------- small-GEMM sweep (5 slices, K=128, M=NA) ----------------
// z 0-3: EW_h = embs_h @ Wa_bot  (N=64, 256-row tiles; BT = WaT rows 64-127)
// z 4  : ZWb  = zbf @ [Wa_top|Wa_bot]  (N=128)
__global__ __launch_bounds__(256) void gemm_sweep(
    const unsigned short* __restrict__ embs, const unsigned short* __restrict__ zbf,
    const unsigned short* __restrict__ WaT,
    unsigned short* __restrict__ EW, unsigned short* __restrict__ ZWb)
{
  const int zi = blockIdx.z;
  const bool ew = zi < 4;
  const int row0 = blockIdx.x * (ew ? 256 : 128);
  if (row0 >= NA) return;                        // trims ew grid to 196 blocks
  const unsigned short* A  = ew ? embs + (size_t)zi * NA * NC : zbf;
  const unsigned short* BT = ew ? WaT + 64 * 128 : WaT;
  unsigned short* Cb       = ew ? EW + (size_t)zi * NA * AH : ZWb;
  const int N = ew ? 64 : 128;

  __shared__ unsigned short As[256 * 32];
  __shared__ unsigned short Bs[128 * 32];
  const int tid = threadIdx.x;
  const int wave = tid >> 6, lane = tid & 63;
  const int wr = ew ? wave * 64 : (wave >> 1) * 64;
  const int wc = ew ? 0 : (wave & 1) * 64;
  f32x4 acc[4][4];
  #pragma unroll
  for (int m = 0; m < 4; m++)
    #pragma unroll
    for (int n = 0; n < 4; n++) acc[m][n] = (f32x4){0.f, 0.f, 0.f, 0.f};
  const int lrow = lane >> 2, lk = (lane & 3) * 8;

  for (int k0 = 0; k0 < 128; k0 += 32){
    __syncthreads();
    if (ew){
      #pragma unroll
      for (int j = 0; j < 4; j++){               // 256 A rows
        const int rb = (wave * 4 + j) * 16;
        int gr = row0 + rb + lrow; gr = gr < NA ? gr : NA - 1;
        g2l16(A + (size_t)gr * 128 + k0 + lk, As + rb * 32);
      }
      {                                          // 64 B rows (one issue/wave)
        const int rb = wave * 16;
        int gc = rb + lrow; gc = gc < 64 ? gc : 63;
        g2l16(BT + (size_t)gc * 128 + k0 + lk, Bs + rb * 32);
      }
    } else {
      #pragma unroll
      for (int j = 0; j < 2; j++){
        const int rb = (wave * 2 + j) * 16;
        int gr = row0 + rb + lrow; gr = gr < NA ? gr : NA - 1;
        g2l16(A + (size_t)gr * 128 + k0 + lk, As + rb * 32);
        int gc = rb + lrow; gc = gc < N ? gc : N - 1;
        g2l16(BT + (size_t)gc * 128 + k0 + lk, Bs + rb * 32);
      }
    }
    __syncthreads();
    bf16x8 bfr[4];
    #pragma unroll
    for (int n = 0; n < 4; n++)
      bfr[n] = *reinterpret_cast<const bf16x8*>(&Bs[(wc + n * 16 + (lane & 15)) * 32 + (lane >> 4) * 8]);
    #pragma unroll
    for (int m = 0; m < 4; m++){
      bf16x8 a = *reinterpret_cast<const bf16x8*>(&As[(wr + m * 16 + (lane & 15)) * 32 + (lane >> 4) * 8]);
      #pragma unroll
      for (int n = 0; n < 4; n++)
        acc[m][n] = __builtin_amdgcn_mfma_f32_16x16x32_bf16(a, bfr[n], acc[m][n], 0, 0, 0);
    }
  }

  const int rbase = row0 + wr + (lane >> 4) * 4;
  const int cbase = wc + (lane & 15);
  #pragma unroll
  for (int m = 0; m < 4; m++){
    #pragma unroll
    for (int n = 0; n < 4; n++){
      const int col = cbase + n * 16;
      #pragma unroll
      for (int i = 0; i < 4; i++){
        const int row = rbase + m * 16 + i;
        if (row < NA && col < N)
          Cb[(size_t)row * N + col] = f2bf(acc[m][n][i]);
      }
    }
  }
}

// ---------------- two-level binned CSR build ----------------
// binA record: lo32 = val bits, hi32 = (localrow<<17)|col
__global__ __launch_bounds__(256) void binA_kernel(
    const int* __restrict__ adji, const float* __restrict__ adjv,
    int* __restrict__ fill, long long* __restrict__ binned)
{
  const int h = blockIdx.y, tid = threadIdx.x;
  const int e0 = blockIdx.x * 2048;
  __shared__ int lhist[NBUCK], lbase[NBUCK], lfill[NBUCK];
  for (int i = tid; i < NBUCK; i += 256){ lhist[i] = 0; lfill[i] = 0; }
  __syncthreads();
  int rr[8]; unsigned hh[8]; float vv[8];
  #pragma unroll
  for (int k = 0; k < 8; k++){
    int e = e0 + k * 256 + tid;
    bool ok = e < NE;
    int r = ok ? adji[(size_t)h * 2 * NE + e] : -1;
    int c = ok ? adji[(size_t)h * 2 * NE + NE + e] : 0;
    vv[k] = ok ? adjv[(size_t)h * NE + e] : 0.f;
    rr[k] = r;
    hh[k] = ((unsigned)(r & 255) << 17) | (unsigned)c;
    if (ok) atomicAdd(&lhist[r >> 8], 1);
  }
  __syncthreads();
  if (tid < NBUCK) lbase[tid] = atomicAdd(&fill[h * NBUCK + tid], lhist[tid]);
  __syncthreads();
  #pragma unroll
  for (int k = 0; k < 8; k++){
    if (rr[k] >= 0){
      int b = rr[k] >> 8;
      int p = lbase[b] + atomicAdd(&lfill[b], 1);
      if (p < CAPB)
        binned[((size_t)(h * NBUCK + b)) * CAPB + p] =
            ((long long)hh[k] << 32) | (unsigned)__float_as_int(vv[k]);
    }
  }
}

__global__ __launch_bounds__(1024) void bscan_kernel(const int* __restrict__ fill,
                                                     int* __restrict__ bbase, int* __restrict__ offs){
  __shared__ int tmp[1024];
  int tid = threadIdx.x;
  int v = (tid < NHOP * NBUCK) ? fill[tid] : 0;
  tmp[tid] = v; __syncthreads();
  for (int o = 1; o < 1024; o <<= 1){
    int t = (tid >= o) ? tmp[tid - o] : 0;
    __syncthreads();
    tmp[tid] += t;
    __syncthreads();
  }
  if (tid < NHOP * NBUCK) bbase[tid] = tmp[tid] - v;
  if (tid == 0) offs[NHOP * NA] = NHOP * NE;
}

// binB output record: lo32 = val bits, hi32 = col<<6 (z row dword offset, gather adds lane)
__global__ __launch_bounds__(256) void binB_kernel(
    const int* __restrict__ fill, const int* __restrict__ bbase,
    const long long* __restrict__ binned,
    int* __restrict__ offs, long long* __restrict__ pvc)
{
  const int b = blockIdx.x, h = blockIdx.y, tid = threadIdx.x;
  const int hb = h * NBUCK + b;
  const int cnt = min(fill[hb], CAPB);
  const long long* src = binned + (size_t)hb * CAPB;
  const int gbase = bbase[hb];
  const int rowbase = b << 8;
  const int nrows = min(256, NA - rowbase);
  __shared__ long long sdata[CAPB];
  __shared__ int lhist[256], lpre[256], lfill2[256];
  lhist[tid] = 0; lfill2[tid] = 0;
  __syncthreads();
  for (int p = tid; p < cnt; p += 256)
    atomicAdd(&lhist[(unsigned)(src[p] >> 32) >> 17], 1);
  __syncthreads();
  int v = lhist[tid]; lpre[tid] = v; __syncthreads();
  for (int o = 1; o < 256; o <<= 1){
    int t = (tid >= o) ? lpre[tid - o] : 0;
    __syncthreads();
    lpre[tid] += t;
    __syncthreads();
  }
  int excl = lpre[tid] - v;
  if (tid < nrows) offs[h * NA + rowbase + tid] = gbase + excl;
  lpre[tid] = excl;
  __syncthreads();
  for (int p = tid; p < cnt; p += 256){
    long long rec = src[p];
    unsigned hi = (unsigned)(rec >> 32);
    int lr = hi >> 17;
    long long out = (rec & 0xffffffffLL) | ((long long)((hi & 0x1ffffu) << 6) << 32);
    int pos = lpre[lr] + atomicAdd(&lfill2[lr], 1);
    if (pos < CAPB) sdata[pos] = out;
    else            pvc[(size_t)gbase + pos] = out;
  }
  __syncthreads();
  for (int p = tid; p < cnt; p += 256)
    pvc[(size_t)gbase + p] = sdata[p];
}

// ---------------- single-pass 128-channel gather, wave-per-row (converged) ----------------
// Gathers over zg = z@Wg -> emits embs DIRECTLY (A_h z Wg = (A_h zg)).
#define GR 4
__global__ __launch_bounds__(256) void gather_kernel(
    const int* __restrict__ offs, const long long* __restrict__ pvc,
    const unsigned short* __restrict__ zg, unsigned short* __restrict__ embs)
{
  const int h = blockIdx.y;
  const int w = threadIdx.x >> 6, lane = threadIdx.x & 63;
  const int row = blockIdx.x * GR + w;
  const int base = h * NA + row;
  const int s = offs[base], e = offs[base + 1];
  __shared__ alignas(16) long long srec[GR][64];
  const unsigned* z32 = (const unsigned*)zg;    // [NA][64] dwords (2 bf16 each)
  const int4* sr2 = (const int4*)&srec[w][0];
  float a0 = 0.f, a1 = 0.f, b0 = 0.f, b1 = 0.f;
  for (int p0 = s; p0 < e; p0 += 64){
    long long r = 0;
    if (p0 + lane < e) r = __builtin_nontemporal_load(&pvc[p0 + lane]);
    srec[w][lane] = r;                          // all 64 lanes write -> padding stays 0
    const int quads = (min(64, e - p0) + 3) >> 2;
    #pragma unroll 4
    for (int q = 0; q < quads; q++){
      int4 ra = sr2[2 * q], rb = sr2[2 * q + 1];  // 4 records, wave-uniform broadcast
      unsigned z0 = z32[(unsigned)ra.y + lane];
      unsigned z1 = z32[(unsigned)ra.w + lane];
      unsigned z2 = z32[(unsigned)rb.y + lane];
      unsigned z3 = z32[(unsigned)rb.w + lane];
      float v0 = uasf((unsigned)ra.x), v1 = uasf((unsigned)ra.z);
      float v2 = uasf((unsigned)rb.x), v3 = uasf((unsigned)rb.z);
      a0 += v0 * uasf(z0 << 16); a1 += v0 * uasf(z0 & 0xffff0000u);
      b0 += v1 * uasf(z1 << 16); b1 += v1 * uasf(z1 & 0xffff0000u);
      a0 += v2 * uasf(z2 << 16); a1 += v2 * uasf(z2 & 0xffff0000u);
      b0 += v3 * uasf(z3 << 16); b1 += v3 * uasf(z3 & 0xffff0000u);
    }
  }
  ushort2 o; o.x = f2bf(a0 + b0); o.y = f2bf(a1 + b1);
  *reinterpret_cast<ushort2*>(embs + (size_t)base * NC + lane * 2) = o;
}

// ---------------- fused attention epilogue (bf16 anchor + bf16 ZW) ----------------
__global__ __launch_bounds__(256) void final_kernel(
    const unsigned short* __restrict__ zbf, const unsigned short* __restrict__ embs,
    const unsigned short* __restrict__ ZWb, const unsigned short* __restrict__ EW,
    const float* __restrict__ ba, const float* __restrict__ va,
    const int* __restrict__ idx, float* __restrict__ out)
{
  int tid = threadIdx.x, wave = tid >> 6, lane = tid & 63;
  int n = blockIdx.x * 4 + wave;
  if (n >= NA) return;
  int an = idx[n];
  float qa = bf2f(ZWb[(size_t)an * NC + lane]) + ba[lane];
  float vaj = va[lane];
  float sc[5];
  {
    float s0 = bf2f(ZWb[(size_t)an * NC + 64 + lane]);
    float t = tanh_fast(qa + s0) * vaj;
    #pragma unroll
    for (int o = 32; o; o >>= 1) t += __shfl_xor(t, o);
    sc[0] = t;
  }
  #pragma unroll
  for (int h = 1; h < 5; h++){
    float sh = bf2f(EW[((size_t)(h - 1) * NA + n) * AH + lane]);
    float t = tanh_fast(qa + sh) * vaj;
    #pragma unroll
    for (int o = 32; o; o >>= 1) t += __shfl_xor(t, o);
    sc[h] = t;
  }
  float m = sc[0];
  #pragma unroll
  for (int h = 1; h < 5; h++) m = fmaxf(m, sc[h]);
  float al[5], den = 0.f;
  #pragma unroll
  for (int h = 0; h < 5; h++){ al[h] = __expf(sc[h] - m); den += al[h]; }
  float inv = 1.f / den;
  float o0 = al[0] * bf2f(zbf[(size_t)an * NC + lane]);
  float o1 = al[0] * bf2f(zbf[(size_t)an * NC + 64 + lane]);
  #pragma unroll
  for (int h = 1; h < 5; h++){
    o0 += al[h] * bf2f(embs[((size_t)(h - 1) * NA + n) * NC + lane]);
    o1 += al[h] * bf2f(embs[((size_t)(h - 1) * NA + n) * NC + 64 + lane]);
  }
  o0 *= inv; o1 *= inv;
  float mx = fmaxf(o0, o1);
  #pragma unroll
  for (int o = 32; o; o >>= 1) mx = fmaxf(mx, __shfl_xor(mx, o));
  float se = __expf(o0 - mx) + __expf(o1 - mx);
  #pragma unroll
  for (int o = 32; o; o >>= 1) se += __shfl_xor(se, o);
  float ls = __logf(se);
  out[(size_t)n * NC + lane]      = o0 - mx - ls;
  out[(size_t)n * NC + 64 + lane] = o1 - mx - ls;
}

// ---------------- launch ----------------

extern "C" void kernel_launch(void* const* d_in, const int* in_sizes, int n_in,
                              void* d_out, int out_size, void* d_ws, size_t ws_size,
                              hipStream_t stream)
{
  const float* x    = (const float*)d_in[0];
  const float* W1   = (const float*)d_in[1];
  const float* W2   = (const float*)d_in[2];
  const float* b2   = (const float*)d_in[3];
  const float* Wg   = (const float*)d_in[4];
  const float* Wa   = (const float*)d_in[5];
  const float* ba   = (const float*)d_in[6];
  const float* va   = (const float*)d_in[7];
  const float* adjv = (const float*)d_in[8];
  const int*   adji = (const int*)d_in[9];
  const int*   idx  = (const int*)d_in[10];
  float* out = (float*)d_out;
  (void)in_sizes; (void)n_in; (void)out_size; (void)ws_size;

  char* w = (char*)d_ws;
  auto alloc = [&](size_t b) -> char* { char* p = w; w += (b + 255) & ~(size_t)255; return p; };
  unsigned short* Scr1 = (unsigned short*)alloc((size_t)NA * NFEAT * 2);  // 51.2MB: binned -> embs
  unsigned short* Hbuf = (unsigned short*)alloc((size_t)NA * HID * 2);    // 51.2MB: H
  unsigned short* W1T  = (unsigned short*)alloc((size_t)HID * NFEAT * 2);
  unsigned short* W2cT = (unsigned short*)alloc((size_t)256 * HID * 2);   // [W2 | W2@Wg]^T
  unsigned short* WaT  = (unsigned short*)alloc((size_t)NC * NC * 2);
  float*          b2c  = (float*)alloc(256 * 4);
  unsigned short* zbf  = (unsigned short*)alloc((size_t)NA * NC * 2);
  unsigned short* zg   = (unsigned short*)alloc((size_t)NA * NC * 2);     // z@Wg
  unsigned short* ZWb  = (unsigned short*)alloc((size_t)NA * NC * 2);
  int* fill  = (int*)alloc((size_t)NHOP * NBUCK * 4);
  int* bbase = (int*)alloc((size_t)NHOP * NBUCK * 4);
  int* offs  = (int*)alloc(((size_t)NHOP * NA + 1) * 4);
  long long* pvc = (long long*)alloc((size_t)NHOP * NE * 8);              // CSR records {val, col<<6}
  long long* binned     = (long long*)Scr1;      // live binA..binB
  unsigned short* embs  = Scr1;                  // [4][NA][NC] bf16 (gather output, after binB)
  unsigned short* EW    = (unsigned short*)pvc;  // [4][NA][64] bf16 (pvc dead after gather)

  // merged weight prep (W1T, W2cT, WaT, b2c; zeroes fill)
  prep_kernel<<<dim3(1605), 256, 0, stream>>>(W1, W2, Wg, Wa, b2, W1T, W2cT, WaT, b2c, fill);

  // H = relu(x@W1)  ->  [z | zg] = H @ [W2 | W2@Wg] + b2c   (128x256-tile GEMMs)
  gemm_wide<0><<<dim3(784), 256, 0, stream>>>(x, W1T, Hbuf, nullptr, nullptr);
  gemm_wide<1><<<dim3(391), 256, 0, stream>>>(Hbuf, W2cT, zbf, zg, b2c);

  // CSR build: bin -> scan -> fine sort
  binA_kernel<<<dim3((NE + 2047) / 2048, NHOP), 256, 0, stream>>>(adji, adjv, fill, binned);
  bscan_kernel<<<dim3(1), 1024, 0, stream>>>(fill, bbase, offs);
  binB_kernel<<<dim3(NBUCK, NHOP), 256, 0, stream>>>(fill, bbase, binned, offs, pvc);

  // gather over zg -> embs directly; sweep: EW (4x) + ZW
  gather_kernel<<<dim3(NA / GR, NHOP), 256, 0, stream>>>(offs, pvc, zg, embs);
  gemm_sweep<<<dim3(391, 1, 5), 256, 0, stream>>>(embs, zbf, WaT, EW, ZWb);

  // fused softmax-attention + log_softmax
  final_kernel<<<dim3(NA / 4), 256, 0, stream>>>(zbf, embs, ZWb, EW, ba, va, idx, out);
}

// Round 15
// 336.841 us; speedup vs baseline: 1.2433x; 1.2433x over previous
//
#include <hip/hip_runtime.h>

#define NA    50000
#define NFEAT 512
#define HID   512
#define NC    128
#define AH    64
#define NE    800000
#define NHOP  4
#define NBUCK 196      // ceil(NA/256) buckets of 256 rows
#define CAPB  5120     // per-bucket capacity (mean 4082 -> 16 sigma headroom)

typedef __bf16 bf16x8 __attribute__((ext_vector_type(8)));
typedef float  f32x4  __attribute__((ext_vector_type(4)));

__device__ __forceinline__ unsigned short f2bf(float f){
  union { float f; unsigned u; } a; a.f = f;
  return (unsigned short)((a.u + 0x7fffu + ((a.u >> 16) & 1u)) >> 16);  // RNE
}
__device__ __forceinline__ float bf2f(unsigned short h){
  union { unsigned u; float f; } a; a.u = ((unsigned)h) << 16;
  return a.f;
}
__device__ __forceinline__ float uasf(unsigned u){
  union { unsigned u; float f; } a; a.u = u;
  return a.f;
}
__device__ __forceinline__ float tanh_fast(float x){
  x = fminf(15.f, fmaxf(-15.f, x));
  float e = __expf(2.f * x);
  return (e - 1.f) / (e + 1.f);
}

__device__ __forceinline__ void g2l16(const void* g, void* l){
  __builtin_amdgcn_global_load_lds(
      (const __attribute__((address_space(1))) void*)g,
      (__attribute__((address_space(3))) void*)l, 16, 0, 0);
}

// ---------------- merged weight prep + fill-zero (one launch) ----------------
__global__ void prep_kernel(const float* __restrict__ W1, const float* __restrict__ W2,
                            const float* __restrict__ Wg, const float* __restrict__ Wa,
                            unsigned short* __restrict__ W1T, unsigned short* __restrict__ W2T,
                            unsigned short* __restrict__ WgT, unsigned short* __restrict__ WaT,
                            unsigned short* __restrict__ WfuseT, int* __restrict__ fill){
  const int b = blockIdx.x, tid = threadIdx.x;
  if (b < 1024){
    int i = b * 256 + tid;                       // 262144: W1T [512][512] = W1^T
    int n = i >> 9, k = i & 511;
    W1T[i] = f2bf(W1[(size_t)k * HID + n]);
  } else if (b < 1280){
    int i = (b - 1024) * 256 + tid;              // 65536: W2T [128][512] = W2^T
    int n = i >> 9, k = i & 511;
    W2T[i] = f2bf(W2[(size_t)k * NC + n]);
  } else if (b < 1344){
    int i = (b - 1280) * 256 + tid;              // 16384: WgT [128][128] = Wg^T
    int n = i >> 7, k = i & 127;
    WgT[i] = f2bf(Wg[(size_t)k * NC + n]);
  } else if (b < 1408){
    int i = (b - 1344) * 256 + tid;              // 16384: WaT packed [Wa_top|Wa_bot]
    int n = i >> 7, k = i & 127;
    float v = (n < 64) ? Wa[(size_t)k * AH + n] : Wa[(size_t)(128 + k) * AH + (n - 64)];
    WaT[i] = f2bf(v);
  } else if (b < 1440){
    int i = (b - 1408) * 256 + tid;              // 8192: Wfuse[j][n] = sum_k Wa_bot[k][j]*Wg[n][k]
    int j = i >> 7, n = i & 127;
    float s = 0.f;
    for (int k = 0; k < 128; k++)
      s += Wa[(size_t)(128 + k) * AH + j] * Wg[(size_t)n * 128 + k];
    WfuseT[i] = f2bf(s);
  } else {
    int i = (b - 1440) * 256 + tid;              // zero fill[784]
    if (i < NHOP * NBUCK) fill[i] = 0;
  }
}

// ---------------- bf16 MFMA GEMM:  C = A[M,K] x BT[N,K]^T ----------------
// OP: 0 relu->bf16   1 +bias->bf16
// SWZ: XCD-affine dispatch (4 col-blocks of a row-block on one XCD)
// AF32: A f32 in global; reg-staged (load f32 -> cvt bf16 -> ds_write_b128 into
//       the SAME bf16 LDS layout; write addr = lane*16, conflict-free).
// NOTE r14: wider tiles (acc[4][8], 144 VGPR) hit the occupancy cliff (8.8%) --
// 128x128 with 64 acc VGPR/wave is the empirical optimum for this thin-K shape.
template<int OP, int SWZ, int AF32>
__global__ __launch_bounds__(256) void gemm_bt(
    const void* __restrict__ Avoid, const unsigned short* __restrict__ BT,
    unsigned short* __restrict__ Cb, const float* __restrict__ bias,
    int M, int N, int K)
{
  int row0, col0;
  if (SWZ){
    const int xcd = blockIdx.x & 7, slot = blockIdx.x >> 3;
    const int r = xcd * 49 + (slot >> 2);
    if (r >= 391) return;
    row0 = r * 128; col0 = (slot & 3) * 128;
  } else {
    row0 = blockIdx.x * 128; col0 = blockIdx.y * 128;
  }
  const unsigned short* A16 = (const unsigned short*)Avoid;
  const float*          A32 = (const float*)Avoid;
  __shared__ unsigned short As[128 * 32];
  __shared__ unsigned short Bs[128 * 32];
  const int tid = threadIdx.x;
  const int wave = tid >> 6, lane = tid & 63;
  const int wr = (wave >> 1) * 64, wc = (wave & 1) * 64;
  f32x4 acc[4][4];
  #pragma unroll
  for (int m = 0; m < 4; m++)
    #pragma unroll
    for (int n = 0; n < 4; n++) acc[m][n] = (f32x4){0.f, 0.f, 0.f, 0.f};
  const int lrow = lane >> 2, lk = (lane & 3) * 8;

  for (int k0 = 0; k0 < K; k0 += 32){
    __syncthreads();
    #pragma unroll
    for (int j = 0; j < 2; j++){
      const int rb = (wave * 2 + j) * 16;       // wave-uniform LDS base row
      const int ra = rb + lrow;
      int gr = row0 + ra; gr = gr < M ? gr : M - 1;
      if (AF32){
        const float* src = A32 + (size_t)gr * K + k0 + lk;
        float4 f0 = *reinterpret_cast<const float4*>(src);
        float4 f1 = *reinterpret_cast<const float4*>(src + 4);
        bf16x8 a;
        a[0] = (__bf16)f0.x; a[1] = (__bf16)f0.y; a[2] = (__bf16)f0.z; a[3] = (__bf16)f0.w;
        a[4] = (__bf16)f1.x; a[5] = (__bf16)f1.y; a[6] = (__bf16)f1.z; a[7] = (__bf16)f1.w;
        *reinterpret_cast<bf16x8*>(&As[ra * 32 + lk]) = a;    // addr = lane*16: linear
      } else {
        g2l16(A16 + (size_t)gr * K + k0 + lk, As + rb * 32);
      }
      int gc = col0 + ra; gc = gc < N ? gc : N - 1;
      g2l16(BT + (size_t)gc * K + k0 + lk, Bs + rb * 32);
    }
    __syncthreads();
    bf16x8 af[4], bfr[4];
    #pragma unroll
    for (int m = 0; m < 4; m++)
      af[m] = *reinterpret_cast<const bf16x8*>(&As[(wr + m * 16 + (lane & 15)) * 32 + (lane >> 4) * 8]);
    #pragma unroll
    for (int n = 0; n < 4; n++)
      bfr[n] = *reinterpret_cast<const bf16x8*>(&Bs[(wc + n * 16 + (lane & 15)) * 32 + (lane >> 4) * 8]);
    #pragma unroll
    for (int m = 0; m < 4; m++)
      #pragma unroll
      for (int n = 0; n < 4; n++)
        acc[m][n] = __builtin_amdgcn_mfma_f32_16x16x32_bf16(af[m], bfr[n], acc[m][n], 0, 0, 0);
  }

  const int rbase = row0 + wr + (lane >> 4) * 4;
  const int cbase = col0 + wc + (lane & 15);
  #pragma unroll
  for (int m = 0; m < 4; m++){
    #pragma unroll
    for (int n = 0; n < 4; n++){
      const int col = cbase + n * 16;
      #pragma unroll
      for (int i = 0; i < 4; i++){
        const int row = rbase + m * 16 + i;
        if (row < M && col < N){
          float v = acc[m][n][i];
          if (OP == 0){ v = v > 0.f ? v : 0.f; }
          else        { v += bias[col]; }
          Cb[(size_t)row * N + col] = f2bf(v);
        }
      }
    }
  }
}

// ---------------- merged small-GEMM sweep (9 slices, K=128, M=NA) ----------------
// z 0-3: embs_h = agg_h @ Wg      (N=128, 128-row tiles)
// z 4-7: EWf_h  = agg_h @ Wfuse   (N=64,  256-row tiles, full wave util)
// z 8  : ZWb    = zbf @ [Wa_top|Wa_bot]  (N=128, bf16 out)
__global__ __launch_bounds__(256) void gemm_sweep(
    const unsigned short* __restrict__ aggbf, const unsigned short* __restrict__ zbf,
    const unsigned short* __restrict__ WgT, const unsigned short* __restrict__ WfuseT,
    const unsigned short* __restrict__ WaT,
    unsigned short* __restrict__ embs, unsigned short* __restrict__ EW,
    unsigned short* __restrict__ ZWb)
{
  const int zi = blockIdx.z;
  const bool ew = (zi >= 4 && zi < 8);
  const int row0 = blockIdx.x * (ew ? 256 : 128);
  if (row0 >= NA) return;                        // trims ew grid to 196 blocks
  const unsigned short* A; const unsigned short* BT; unsigned short* Cb; int N;
  if (zi < 4)      { A = aggbf + (size_t)zi * NA * NC;       BT = WgT;    Cb = embs + (size_t)zi * NA * NC; N = 128; }
  else if (ew)     { A = aggbf + (size_t)(zi - 4) * NA * NC; BT = WfuseT; Cb = EW + (size_t)(zi - 4) * NA * AH; N = 64; }
  else             { A = zbf;                                BT = WaT;    Cb = ZWb; N = 128; }

  __shared__ unsigned short As[256 * 32];
  __shared__ unsigned short Bs[128 * 32];
  const int tid = threadIdx.x;
  const int wave = tid >> 6, lane = tid & 63;
  const int wr = ew ? wave * 64 : (wave >> 1) * 64;
  const int wc = ew ? 0 : (wave & 1) * 64;
  f32x4 acc[4][4];
  #pragma unroll
  for (int m = 0; m < 4; m++)
    #pragma unroll
    for (int n = 0; n < 4; n++) acc[m][n] = (f32x4){0.f, 0.f, 0.f, 0.f};
  const int lrow = lane >> 2, lk = (lane & 3) * 8;

  for (int k0 = 0; k0 < 128; k0 += 32){
    __syncthreads();
    if (ew){
      #pragma unroll
      for (int j = 0; j < 4; j++){               // 256 A rows
        const int rb = (wave * 4 + j) * 16;
        int gr = row0 + rb + lrow; gr = gr < NA ? gr : NA - 1;
        g2l16(A + (size_t)gr * 128 + k0 + lk, As + rb * 32);
      }
      {                                          // 64 B rows (one issue/wave)
        const int rb = wave * 16;
        int gc = rb + lrow; gc = gc < 64 ? gc : 63;
        g2l16(BT + (size_t)gc * 128 + k0 + lk, Bs + rb * 32);
      }
    } else {
      #pragma unroll
      for (int j = 0; j < 2; j++){
        const int rb = (wave * 2 + j) * 16;
        int gr = row0 + rb + lrow; gr = gr < NA ? gr : NA - 1;
        g2l16(A + (size_t)gr * 128 + k0 + lk, As + rb * 32);
        int gc = rb + lrow; gc = gc < N ? gc : N - 1;
        g2l16(BT + (size_t)gc * 128 + k0 + lk, Bs + rb * 32);
      }
    }
    __syncthreads();
    bf16x8 bfr[4];
    #pragma unroll
    for (int n = 0; n < 4; n++)
      bfr[n] = *reinterpret_cast<const bf16x8*>(&Bs[(wc + n * 16 + (lane & 15)) * 32 + (lane >> 4) * 8]);
    #pragma unroll
    for (int m = 0; m < 4; m++){
      bf16x8 a = *reinterpret_cast<const bf16x8*>(&As[(wr + m * 16 + (lane & 15)) * 32 + (lane >> 4) * 8]);
      #pragma unroll
      for (int n = 0; n < 4; n++)
        acc[m][n] = __builtin_amdgcn_mfma_f32_16x16x32_bf16(a, bfr[n], acc[m][n], 0, 0, 0);
    }
  }

  const int rbase = row0 + wr + (lane >> 4) * 4;
  const int cbase = wc + (lane & 15);
  #pragma unroll
  for (int m = 0; m < 4; m++){
    #pragma unroll
    for (int n = 0; n < 4; n++){
      const int col = cbase + n * 16;
      #pragma unroll
      for (int i = 0; i < 4; i++){
        const int row = rbase + m * 16 + i;
        if (row < NA && col < N)
          Cb[(size_t)row * N + col] = f2bf(acc[m][n][i]);
      }
    }
  }
}

// ---------------- two-level binned CSR build ----------------
// binA record: lo32 = val bits, hi32 = (localrow<<17)|col
__global__ __launch_bounds__(256) void binA_kernel(
    const int* __restrict__ adji, const float* __restrict__ adjv,
    int* __restrict__ fill, long long* __restrict__ binned)
{
  const int h = blockIdx.y, tid = threadIdx.x;
  const int e0 = blockIdx.x * 2048;
  __shared__ int lhist[NBUCK], lbase[NBUCK], lfill[NBUCK];
  for (int i = tid; i < NBUCK; i += 256){ lhist[i] = 0; lfill[i] = 0; }
  __syncthreads();
  int rr[8]; unsigned hh[8]; float vv[8];
  #pragma unroll
  for (int k = 0; k < 8; k++){
    int e = e0 + k * 256 + tid;
    bool ok = e < NE;
    int r = ok ? adji[(size_t)h * 2 * NE + e] : -1;
    int c = ok ? adji[(size_t)h * 2 * NE + NE + e] : 0;
    vv[k] = ok ? adjv[(size_t)h * NE + e] : 0.f;
    rr[k] = r;
    hh[k] = ((unsigned)(r & 255) << 17) | (unsigned)c;
    if (ok) atomicAdd(&lhist[r >> 8], 1);
  }
  __syncthreads();
  if (tid < NBUCK) lbase[tid] = atomicAdd(&fill[h * NBUCK + tid], lhist[tid]);
  __syncthreads();
  #pragma unroll
  for (int k = 0; k < 8; k++){
    if (rr[k] >= 0){
      int b = rr[k] >> 8;
      int p = lbase[b] + atomicAdd(&lfill[b], 1);
      if (p < CAPB)
        binned[((size_t)(h * NBUCK + b)) * CAPB + p] =
            ((long long)hh[k] << 32) | (unsigned)__float_as_int(vv[k]);
    }
  }
}

__global__ __launch_bounds__(1024) void bscan_kernel(const int* __restrict__ fill,
                                                     int* __restrict__ bbase, int* __restrict__ offs){
  __shared__ int tmp[1024];
  int tid = threadIdx.x;
  int v = (tid < NHOP * NBUCK) ? fill[tid] : 0;
  tmp[tid] = v; __syncthreads();
  for (int o = 1; o < 1024; o <<= 1){
    int t = (tid >= o) ? tmp[tid - o] : 0;
    __syncthreads();
    tmp[tid] += t;
    __syncthreads();
  }
  if (tid < NHOP * NBUCK) bbase[tid] = tmp[tid] - v;
  if (tid == 0) offs[NHOP * NA] = NHOP * NE;
}

// binB output record: lo32 = val bits, hi32 = col<<6 (z row dword offset, gather adds lane)
__global__ __launch_bounds__(256) void binB_kernel(
    const int* __restrict__ fill, const int* __restrict__ bbase,
    const long long* __restrict__ binned,
    int* __restrict__ offs, long long* __restrict__ pvc)
{
  const int b = blockIdx.x, h = blockIdx.y, tid = threadIdx.x;
  const int hb = h * NBUCK + b;
  const int cnt = min(fill[hb], CAPB);
  const long long* src = binned + (size_t)hb * CAPB;
  const int gbase = bbase[hb];
  const int rowbase = b << 8;
  const int nrows = min(256, NA - rowbase);
  __shared__ long long sdata[CAPB];
  __shared__ int lhist[256], lpre[256], lfill2[256];
  lhist[tid] = 0; lfill2[tid] = 0;
  __syncthreads();
  for (int p = tid; p < cnt; p += 256)
    atomicAdd(&lhist[(unsigned)(src[p] >> 32) >> 17], 1);
  __syncthreads();
  int v = lhist[tid]; lpre[tid] = v; __syncthreads();
  for (int o = 1; o < 256; o <<= 1){
    int t = (tid >= o) ? lpre[tid - o] : 0;
    __syncthreads();
    lpre[tid] += t;
    __syncthreads();
  }
  int excl = lpre[tid] - v;
  if (tid < nrows) offs[h * NA + rowbase + tid] = gbase + excl;
  lpre[tid] = excl;
  __syncthreads();
  for (int p = tid; p < cnt; p += 256){
    long long rec = src[p];
    unsigned hi = (unsigned)(rec >> 32);
    int lr = hi >> 17;
    long long out = (rec & 0xffffffffLL) | ((long long)((hi & 0x1ffffu) << 6) << 32);
    int pos = lpre[lr] + atomicAdd(&lfill2[lr], 1);
    if (pos < CAPB) sdata[pos] = out;
    else            pvc[(size_t)gbase + pos] = out;
  }
  __syncthreads();
  for (int p = tid; p < cnt; p += 256)
    pvc[(size_t)gbase + p] = sdata[p];
}

// ---------------- single-pass 128-channel gather, wave-per-row (converged) ----------------
#define GR 4
__global__ __launch_bounds__(256) void gather_kernel(
    const int* __restrict__ offs, const long long* __restrict__ pvc,
    const unsigned short* __restrict__ zbf, unsigned short* __restrict__ aggbf)
{
  const int h = blockIdx.y;
  const int w = threadIdx.x >> 6, lane = threadIdx.x & 63;
  const int row = blockIdx.x * GR + w;
  const int base = h * NA + row;
  const int s = offs[base], e = offs[base + 1];
  __shared__ alignas(16) long long srec[GR][64];
  const unsigned* z32 = (const unsigned*)zbf;   // [NA][64] dwords (2 bf16 each)
  const int4* sr2 = (const int4*)&srec[w][0];
  float a0 = 0.f, a1 = 0.f, b0 = 0.f, b1 = 0.f;
  for (int p0 = s; p0 < e; p0 += 64){
    long long r = 0;
    if (p0 + lane < e) r = __builtin_nontemporal_load(&pvc[p0 + lane]);
    srec[w][lane] = r;                          // all 64 lanes write -> padding stays 0
    const int quads = (min(64, e - p0) + 3) >> 2;
    #pragma unroll 4
    for (int q = 0; q < quads; q++){
      int4 ra = sr2[2 * q], rb = sr2[2 * q + 1];  // 4 records, wave-uniform broadcast
      unsigned z0 = z32[(unsigned)ra.y + lane];
      unsigned z1 = z32[(unsigned)ra.w + lane];
      unsigned z2 = z32[(unsigned)rb.y + lane];
      unsigned z3 = z32[(unsigned)rb.w + lane];
      float v0 = uasf((unsigned)ra.x), v1 = uasf((unsigned)ra.z);
      float v2 = uasf((unsigned)rb.x), v3 = uasf((unsigned)rb.z);
      a0 += v0 * uasf(z0 << 16); a1 += v0 * uasf(z0 & 0xffff0000u);
      b0 += v1 * uasf(z1 << 16); b1 += v1 * uasf(z1 & 0xffff0000u);
      a0 += v2 * uasf(z2 << 16); a1 += v2 * uasf(z2 & 0xffff0000u);
      b0 += v3 * uasf(z3 << 16); b1 += v3 * uasf(z3 & 0xffff0000u);
    }
  }
  ushort2 o; o.x = f2bf(a0 + b0); o.y = f2bf(a1 + b1);
  *reinterpret_cast<ushort2*>(aggbf + (size_t)base * NC + lane * 2) = o;
}

// ---------------- fused attention epilogue (bf16 anchor + bf16 ZW) ----------------
__global__ __launch_bounds__(256) void final_kernel(
    const unsigned short* __restrict__ zbf, const unsigned short* __restrict__ embs,
    const unsigned short* __restrict__ ZWb, const unsigned short* __restrict__ EW,
    const float* __restrict__ ba, const float* __restrict__ va,
    const int* __restrict__ idx, float* __restrict__ out)
{
  int tid = threadIdx.x, wave = tid >> 6, lane = tid & 63;
  int n = blockIdx.x * 4 + wave;
  if (n >= NA) return;
  int an = idx[n];
  float qa = bf2f(ZWb[(size_t)an * NC + lane]) + ba[lane];
  float vaj = va[lane];
  float sc[5];
  {
    float s0 = bf2f(ZWb[(size_t)an * NC + 64 + lane]);
    float t = tanh_fast(qa + s0) * vaj;
    #pragma unroll
    for (int o = 32; o; o >>= 1) t += __shfl_xor(t, o);
    sc[0] = t;
  }
  #pragma unroll
  for (int h = 1; h < 5; h++){
    float sh = bf2f(EW[((size_t)(h - 1) * NA + n) * AH + lane]);
    float t = tanh_fast(qa + sh) * vaj;
    #pragma unroll
    for (int o = 32; o; o >>= 1) t += __shfl_xor(t, o);
    sc[h] = t;
  }
  float m = sc[0];
  #pragma unroll
  for (int h = 1; h < 5; h++) m = fmaxf(m, sc[h]);
  float al[5], den = 0.f;
  #pragma unroll
  for (int h = 0; h < 5; h++){ al[h] = __expf(sc[h] - m); den += al[h]; }
  float inv = 1.f / den;
  float o0 = al[0] * bf2f(zbf[(size_t)an * NC + lane]);
  float o1 = al[0] * bf2f(zbf[(size_t)an * NC + 64 + lane]);
  #pragma unroll
  for (int h = 1; h < 5; h++){
    o0 += al[h] * bf2f(embs[((size_t)(h - 1) * NA + n) * NC + lane]);
    o1 += al[h] * bf2f(embs[((size_t)(h - 1) * NA + n) * NC + 64 + lane]);
  }
  o0 *= inv; o1 *= inv;
  float mx = fmaxf(o0, o1);
  #pragma unroll
  for (int o = 32; o; o >>= 1) mx = fmaxf(mx, __shfl_xor(mx, o));
  float se = __expf(o0 - mx) + __expf(o1 - mx);
  #pragma unroll
  for (int o = 32; o; o >>= 1) se += __shfl_xor(se, o);
  float ls = __logf(se);
  out[(size_t)n * NC + lane]      = o0 - mx - ls;
  out[(size_t)n * NC + 64 + lane] = o1 - mx - ls;
}

// ---------------- launch ----------------

extern "C" void kernel_launch(void* const* d_in, const int* in_sizes, int n_in,
                              void* d_out, int out_size, void* d_ws, size_t ws_size,
                              hipStream_t stream)
{
  const float* x    = (const float*)d_in[0];
  const float* W1   = (const float*)d_in[1];
  const float* W2   = (const float*)d_in[2];
  const float* b2   = (const float*)d_in[3];
  const float* Wg   = (const float*)d_in[4];
  const float* Wa   = (const float*)d_in[5];
  const float* ba   = (const float*)d_in[6];
  const float* va   = (const float*)d_in[7];
  const float* adjv = (const float*)d_in[8];
  const int*   adji = (const int*)d_in[9];
  const int*   idx  = (const int*)d_in[10];
  float* out = (float*)d_out;
  (void)in_sizes; (void)n_in; (void)out_size; (void)ws_size;

  char* w = (char*)d_ws;
  auto alloc = [&](size_t b) -> char* { char* p = w; w += (b + 255) & ~(size_t)255; return p; };
  unsigned short* Scr1 = (unsigned short*)alloc((size_t)NA * NFEAT * 2);  // 51.2MB: binned -> embs
  unsigned short* Hbuf = (unsigned short*)alloc((size_t)NA * HID * 2);    // 51.2MB: GEMM1 out -> aggbf
  unsigned short* W1T  = (unsigned short*)alloc((size_t)HID * NFEAT * 2);
  unsigned short* W2T  = (unsigned short*)alloc((size_t)NC * HID * 2);
  unsigned short* WgT  = (unsigned short*)alloc((size_t)NC * NC * 2);
  unsigned short* WaT  = (unsigned short*)alloc((size_t)NC * NC * 2);
  unsigned short* WfuseT = (unsigned short*)alloc((size_t)AH * NC * 2);
  unsigned short* zbf  = (unsigned short*)alloc((size_t)NA * NC * 2);
  unsigned short* ZWb  = (unsigned short*)alloc((size_t)NA * NC * 2);
  int* fill  = (int*)alloc((size_t)NHOP * NBUCK * 4);
  int* bbase = (int*)alloc((size_t)NHOP * NBUCK * 4);
  int* offs  = (int*)alloc(((size_t)NHOP * NA + 1) * 4);
  long long* pvc = (long long*)alloc((size_t)NHOP * NE * 8);              // CSR records {val, col<<6}
  long long* binned     = (long long*)Scr1;      // live binA..binB
  unsigned short* embs  = Scr1;                  // [4][NA][NC] bf16 (after binB)
  unsigned short* aggbf = Hbuf;                  // [4][NA][NC] bf16 (after GEMM2)
  unsigned short* EW    = (unsigned short*)pvc;  // [4][NA][64] bf16 (pvc dead after gather)

  // merged weight prep (also zeroes fill)
  prep_kernel<<<dim3(1444), 256, 0, stream>>>(W1, W2, Wg, Wa, W1T, W2T, WgT, WaT, WfuseT, fill);

  // z = relu(x@W1)@W2 + b2   (GEMM1 reads x f32 directly: reg-staged cvt, no cast pass)
  gemm_bt<0, 1, 1><<<dim3(1568, 1, 1), 256, 0, stream>>>(x, W1T, Hbuf, nullptr, NA, HID, NFEAT);
  gemm_bt<1, 0, 0><<<dim3(391, 1, 1), 256, 0, stream>>>(Hbuf, W2T, zbf, b2, NA, NC, HID);

  // CSR build: bin -> scan -> fine sort
  binA_kernel<<<dim3((NE + 2047) / 2048, NHOP), 256, 0, stream>>>(adji, adjv, fill, binned);
  bscan_kernel<<<dim3(1), 1024, 0, stream>>>(fill, bbase, offs);
  binB_kernel<<<dim3(NBUCK, NHOP), 256, 0, stream>>>(fill, bbase, binned, offs, pvc);

  // aggregate (converged), then one merged 9-slice GEMM launch
  gather_kernel<<<dim3(NA / GR, NHOP), 256, 0, stream>>>(offs, pvc, zbf, aggbf);
  gemm_sweep<<<dim3(391, 1, 9), 256, 0, stream>>>(aggbf, zbf, WgT, WfuseT, WaT, embs, EW, ZWb);

  // fused softmax-attention + log_softmax
  final_kernel<<<dim3(NA / 4), 256, 0, stream>>>(zbf, embs, ZWb, EW, ba, va, idx, out);
}